// Round 8
// baseline (1583.213 us; speedup 1.0000x reference)
//
#include <hip/hip_runtime.h>
#include <cmath>

#define HID 64
#define IN_C 128
#define CHUNK 13
#define IDXCAP 512

__device__ __forceinline__ float rl(float v, int k) {
    return __uint_as_float(__builtin_amdgcn_readlane(__float_as_uint(v), k));
}
__device__ __forceinline__ int rli(int v, int k) {
    return __builtin_amdgcn_readlane(v, k);
}
__device__ __forceinline__ float bflo(unsigned u) { return __uint_as_float(u << 16); }
__device__ __forceinline__ float bfhi(unsigned u) { return __uint_as_float(u & 0xffff0000u); }
__device__ __forceinline__ unsigned bfpack(float lo, float hi) {
    unsigned a = __float_as_uint(lo), b = __float_as_uint(hi);
    a = (a + 0x7fffu + ((a >> 16) & 1u)) >> 16;
    b = (b + 0x7fffu + ((b >> 16) & 1u)) & 0xffff0000u;
    return a | b;
}

// ---- VALU cross-lane helpers --------------------------------------------
__device__ __forceinline__ float xadd8(float x) {
    int t = __builtin_amdgcn_update_dpp(0, __float_as_int(x), 0x128, 0xF, 0xF, true);
    return x + __int_as_float(t);
}
#if __has_builtin(__builtin_amdgcn_permlane16_swap)
typedef unsigned uvec2 __attribute__((ext_vector_type(2)));
__device__ __forceinline__ float xadd16(float x) {
    uvec2 r = __builtin_amdgcn_permlane16_swap(__float_as_uint(x), __float_as_uint(x), false, false);
    return __uint_as_float(r[0]) + __uint_as_float(r[1]);
}
#else
__device__ __forceinline__ float xadd16(float x) { return x + __shfl_xor(x, 16); }
#endif
#if __has_builtin(__builtin_amdgcn_permlane32_swap)
typedef unsigned uvec2b __attribute__((ext_vector_type(2)));
__device__ __forceinline__ float xadd32(float x) {
    uvec2b r = __builtin_amdgcn_permlane32_swap(__float_as_uint(x), __float_as_uint(x), false, false);
    return __uint_as_float(r[0]) + __uint_as_float(r[1]);
}
#else
__device__ __forceinline__ float xadd32(float x) { return x + __shfl_xor(x, 32); }
#endif
__device__ __forceinline__ float pairswap(float x) {
    int t = __builtin_amdgcn_update_dpp(0, __float_as_int(x), 0xB1, 0xF, 0xF, true);
    return __int_as_float(t);
}

// ---- CSR build ----------------------------------------------------------

__global__ void k_hist(const int* __restrict__ dst, int* __restrict__ counts, int E) {
    int e = blockIdx.x * blockDim.x + threadIdx.x;
    if (e < E) atomicAdd(&counts[dst[e]], 1);
}

__global__ void k_scan_block(const int* __restrict__ counts, int* __restrict__ row_ptr,
                             int* __restrict__ chunk_sums, int n) {
    __shared__ int s[1024];
    int i = blockIdx.x * 1024 + threadIdx.x;
    int v = (i < n) ? counts[i] : 0;
    s[threadIdx.x] = v;
    __syncthreads();
    for (int off = 1; off < 1024; off <<= 1) {
        int t = (threadIdx.x >= off) ? s[threadIdx.x - off] : 0;
        __syncthreads();
        s[threadIdx.x] += t;
        __syncthreads();
    }
    if (i < n) row_ptr[i] = s[threadIdx.x] - v;   // exclusive
    if (threadIdx.x == 1023) chunk_sums[blockIdx.x] = s[1023];
}

__global__ void k_scan_fix(int* __restrict__ row_ptr, const int* __restrict__ chunk_sums,
                           int n, int total) {
    __shared__ int base_s;
    if (threadIdx.x == 0) {
        int b = 0;
        for (int c = 0; c < (int)blockIdx.x; ++c) b += chunk_sums[c];
        base_s = b;
    }
    __syncthreads();
    int i = blockIdx.x * 1024 + threadIdx.x;
    if (i < n) row_ptr[i] += base_s;
    if (i == 0) row_ptr[n] = total;
}

__global__ void k_fill(const int* __restrict__ src, const int* __restrict__ dst,
                       const int* __restrict__ row_ptr, int* __restrict__ cursor,
                       int* __restrict__ col_idx, int E) {
    int e = blockIdx.x * blockDim.x + threadIdx.x;
    if (e < E) {
        int d = dst[e];
        int pos = row_ptr[d] + atomicAdd(&cursor[d], 1);
        col_idx[pos] = src[e];
    }
}

// ---- input projection: h0(bf16) = relu(x @ lin0_w^T) --------------------
__global__ __launch_bounds__(256) void k_lin0(const float* __restrict__ x,
                                              const float* __restrict__ w,
                                              const float* __restrict__ b,
                                              unsigned* __restrict__ h0, int N) {
    __shared__ float Wt[IN_C * 65];
    for (int i = threadIdx.x; i < IN_C * HID; i += 256) {
        int o = i >> 7, k = i & 127;
        Wt[k * 65 + o] = w[i];
    }
    __syncthreads();
    int lane = threadIdx.x & 63;
    int wid = (blockIdx.x * blockDim.x + threadIdx.x) >> 6;
    int nw = (gridDim.x * blockDim.x) >> 6;
    float bias = b[lane];
    for (int n0 = wid; n0 < N; n0 += 2 * nw) {
        int n1 = n0 + nw;
        bool v1 = n1 < N;
        int n1c = v1 ? n1 : n0;
        float xa0 = x[(size_t)n0 * IN_C + lane];
        float xa1 = x[(size_t)n0 * IN_C + 64 + lane];
        float xb0 = x[(size_t)n1c * IN_C + lane];
        float xb1 = x[(size_t)n1c * IN_C + 64 + lane];
        float acc0 = bias, acc1 = bias;
#pragma unroll
        for (int k = 0; k < 64; ++k) {
            float wv = Wt[k * 65 + lane];
            acc0 = fmaf(rl(xa0, k), wv, acc0);
            acc1 = fmaf(rl(xb0, k), wv, acc1);
        }
#pragma unroll
        for (int k = 0; k < 64; ++k) {
            float wv = Wt[(64 + k) * 65 + lane];
            acc0 = fmaf(rl(xa1, k), wv, acc0);
            acc1 = fmaf(rl(xb1, k), wv, acc1);
        }
        acc0 = fmaxf(acc0, 0.f);
        acc1 = fmaxf(acc1, 0.f);
        float p0 = pairswap(acc0);
        float p1 = pairswap(acc1);
        if ((lane & 1) == 0) {
            h0[(size_t)n0 * 32 + (lane >> 1)] = bfpack(acc0, p0);
            if (v1) h0[(size_t)n1 * 32 + (lane >> 1)] = bfpack(acc1, p1);
        }
    }
}

// ---- fused GCN2 layer ----------------------------------------------------
// Each wave owns CHUNK contiguous nodes: one row_ptr round-trip + one bulk
// coalesced col_idx->LDS round-trip per chunk; per-node gathers then issue
// off LDS-resident indices (no per-node index round-trip). W' = (1-b)I+bW.
__device__ __forceinline__ void mask4(uint4& q, bool v) {
    q.x = v ? q.x : 0u; q.y = v ? q.y : 0u; q.z = v ? q.z : 0u; q.w = v ? q.w : 0u;
}
__device__ __forceinline__ void acc8(float* a, const uint4& q) {
    a[0] += bflo(q.x); a[1] += bfhi(q.x);
    a[2] += bflo(q.y); a[3] += bfhi(q.y);
    a[4] += bflo(q.z); a[5] += bfhi(q.z);
    a[6] += bflo(q.w); a[7] += bfhi(q.w);
}

__global__ __launch_bounds__(256) void k_layer(const uint4* __restrict__ hin,
                                               const uint4* __restrict__ h0,
                                               unsigned* __restrict__ hout,
                                               const float* __restrict__ W,
                                               const int* __restrict__ row_ptr,
                                               const int* __restrict__ col_idx,
                                               float beta, int N) {
    __shared__ uint4 Wp[8 * 64];     // bf16x8 of W'[8k8+0..7][c]
    __shared__ int idxb[4][IDXCAP];  // per-wave index staging
    for (int idx = threadIdx.x; idx < 8 * 64; idx += 256) {
        int k8 = idx >> 6, c = idx & 63;
        float wv[8];
#pragma unroll
        for (int m = 0; m < 8; ++m) {
            int k = 8 * k8 + m;
            float v = beta * W[k * 64 + c];
            if (k == c) v += 1.f - beta;
            wv[m] = v;
        }
        uint4 p;
        p.x = bfpack(wv[0], wv[1]); p.y = bfpack(wv[2], wv[3]);
        p.z = bfpack(wv[4], wv[5]); p.w = bfpack(wv[6], wv[7]);
        Wp[idx] = p;
    }
    __syncthreads();

    int lane = threadIdx.x & 63;
    int wslot = threadIdx.x >> 6;
    int sub = lane >> 3;
    int cg = lane & 7;
    int gw = (blockIdx.x * blockDim.x + threadIdx.x) >> 6;
    int nwv = (gridDim.x * blockDim.x) >> 6;

    for (int chunk = gw; chunk * CHUNK < N; chunk += nwv) {
        int n0 = chunk * CHUNK;
        int cnt = min(CHUNK, N - n0);
        // one per-lane load covers row_ptr[n0..n0+cnt]
        int rp = row_ptr[n0 + min(lane, cnt)];
        int base = rli(rp, 0);
        int tot = rli(rp, cnt) - base;
        int ncap = min(tot, IDXCAP);
        for (int t = lane; t < ncap; t += 64) idxb[wslot][t] = col_idx[base + t];

        for (int i = 0; i < cnt; i += 2) {
            bool vB = (i + 1) < cnt;
            int iB = vB ? (i + 1) : i;
            int rA0 = rli(rp, i), rA1 = rli(rp, i + 1);
            int rB0 = rli(rp, iB), rB1 = rli(rp, iB + 1);
            int bA = rA0 - base, dA = rA1 - rA0;
            int bB = rB0 - base, dB = vB ? rB1 - rB0 : 0;
            int nA = n0 + i, nB = n0 + iB;
            uint4 hqA = h0[(size_t)nA * 8 + cg];
            uint4 hqB = h0[(size_t)nB * 8 + cg];
            int lastA = max(bA + dA - 1, 0);
            int lastB = max(bB + dB - 1, 0);
            float aA[8], aB[8];
#pragma unroll
            for (int c = 0; c < 8; ++c) { aA[c] = 0.f; aB[c] = 0.f; }
            int rmax = max(dA, dB);
            for (int j = 0; j < rmax; j += 16) {
                int p0 = j + sub, p1 = j + 8 + sub;
                int sA0 = min(bA + p0, lastA), sA1 = min(bA + p1, lastA);
                int sB0 = min(bB + p0, lastB), sB1 = min(bB + p1, lastB);
                int iA0 = (sA0 < IDXCAP) ? idxb[wslot][sA0] : col_idx[base + sA0];
                int iA1 = (sA1 < IDXCAP) ? idxb[wslot][sA1] : col_idx[base + sA1];
                int iB0 = (sB0 < IDXCAP) ? idxb[wslot][sB0] : col_idx[base + sB0];
                int iB1 = (sB1 < IDXCAP) ? idxb[wslot][sB1] : col_idx[base + sB1];
                uint4 qA0 = hin[(size_t)iA0 * 8 + cg];
                uint4 qA1 = hin[(size_t)iA1 * 8 + cg];
                uint4 qB0 = hin[(size_t)iB0 * 8 + cg];
                uint4 qB1 = hin[(size_t)iB1 * 8 + cg];
                mask4(qA0, p0 < dA); mask4(qA1, p1 < dA);
                mask4(qB0, p0 < dB); mask4(qB1, p1 < dB);
                acc8(aA, qA0); acc8(aA, qA1);
                acc8(aB, qB0); acc8(aB, qB1);
            }
            // reduce over 8 edge slots — VALU only
#pragma unroll
            for (int c = 0; c < 8; ++c) { aA[c] = xadd8(aA[c]);  aB[c] = xadd8(aB[c]); }
#pragma unroll
            for (int c = 0; c < 8; ++c) { aA[c] = xadd16(aA[c]); aB[c] = xadd16(aB[c]); }
#pragma unroll
            for (int c = 0; c < 8; ++c) { aA[c] = xadd32(aA[c]); aB[c] = xadd32(aB[c]); }

            float zA[8], zB[8];
            zA[0] = 0.9f * aA[0] + 0.1f * bflo(hqA.x);
            zA[1] = 0.9f * aA[1] + 0.1f * bfhi(hqA.x);
            zA[2] = 0.9f * aA[2] + 0.1f * bflo(hqA.y);
            zA[3] = 0.9f * aA[3] + 0.1f * bfhi(hqA.y);
            zA[4] = 0.9f * aA[4] + 0.1f * bflo(hqA.z);
            zA[5] = 0.9f * aA[5] + 0.1f * bfhi(hqA.z);
            zA[6] = 0.9f * aA[6] + 0.1f * bflo(hqA.w);
            zA[7] = 0.9f * aA[7] + 0.1f * bfhi(hqA.w);
            zB[0] = 0.9f * aB[0] + 0.1f * bflo(hqB.x);
            zB[1] = 0.9f * aB[1] + 0.1f * bfhi(hqB.x);
            zB[2] = 0.9f * aB[2] + 0.1f * bflo(hqB.y);
            zB[3] = 0.9f * aB[3] + 0.1f * bfhi(hqB.y);
            zB[4] = 0.9f * aB[4] + 0.1f * bflo(hqB.z);
            zB[5] = 0.9f * aB[5] + 0.1f * bfhi(hqB.z);
            zB[6] = 0.9f * aB[6] + 0.1f * bflo(hqB.w);
            zB[7] = 0.9f * aB[7] + 0.1f * bfhi(hqB.w);

            float gA0 = 0.f, gA1 = 0.f, gA2 = 0.f, gA3 = 0.f;
            float gB0 = 0.f, gB1 = 0.f, gB2 = 0.f, gB3 = 0.f;
#pragma unroll
            for (int k8 = 0; k8 < 8; ++k8) {
                uint4 wp = Wp[k8 * 64 + lane];
                gA0 = fmaf(rl(zA[0], k8), bflo(wp.x), gA0);
                gA1 = fmaf(rl(zA[1], k8), bfhi(wp.x), gA1);
                gA2 = fmaf(rl(zA[2], k8), bflo(wp.y), gA2);
                gA3 = fmaf(rl(zA[3], k8), bfhi(wp.y), gA3);
                gA0 = fmaf(rl(zA[4], k8), bflo(wp.z), gA0);
                gA1 = fmaf(rl(zA[5], k8), bfhi(wp.z), gA1);
                gA2 = fmaf(rl(zA[6], k8), bflo(wp.w), gA2);
                gA3 = fmaf(rl(zA[7], k8), bfhi(wp.w), gA3);
                gB0 = fmaf(rl(zB[0], k8), bflo(wp.x), gB0);
                gB1 = fmaf(rl(zB[1], k8), bfhi(wp.x), gB1);
                gB2 = fmaf(rl(zB[2], k8), bflo(wp.y), gB2);
                gB3 = fmaf(rl(zB[3], k8), bfhi(wp.y), gB3);
                gB0 = fmaf(rl(zB[4], k8), bflo(wp.z), gB0);
                gB1 = fmaf(rl(zB[5], k8), bfhi(wp.z), gB1);
                gB2 = fmaf(rl(zB[6], k8), bflo(wp.w), gB2);
                gB3 = fmaf(rl(zB[7], k8), bfhi(wp.w), gB3);
            }
            float rA = fmaxf((gA0 + gA1) + (gA2 + gA3), 0.f);
            float rB = fmaxf((gB0 + gB1) + (gB2 + gB3), 0.f);
            float rAn = pairswap(rA);
            float rBn = pairswap(rB);
            if ((lane & 1) == 0) {
                hout[(size_t)nA * 32 + (lane >> 1)] = bfpack(rA, rAn);
                if (vB) hout[(size_t)nB * 32 + (lane >> 1)] = bfpack(rB, rBn);
            }
        }
    }
}

// ---- output projection: out = h @ lin1_w^T + b --------------------------
__global__ __launch_bounds__(256) void k_lin1(const unsigned* __restrict__ h,
                                              const float* __restrict__ w,
                                              const float* __restrict__ b,
                                              float* __restrict__ out, int N) {
    __shared__ float Wt[HID * 65];
    for (int i = threadIdx.x; i < HID * HID; i += 256) {
        int o = i >> 6, k = i & 63;
        Wt[k * 65 + o] = w[i];
    }
    __syncthreads();
    int lane = threadIdx.x & 63;
    int wid = (blockIdx.x * blockDim.x + threadIdx.x) >> 6;
    int nw = (gridDim.x * blockDim.x) >> 6;
    float bias = b[lane];
    for (int n0 = wid; n0 < N; n0 += 2 * nw) {
        int n1 = n0 + nw;
        bool v1 = n1 < N;
        int n1c = v1 ? n1 : n0;
        unsigned ua = h[(size_t)n0 * 32 + (lane >> 1)];
        unsigned ub = h[(size_t)n1c * 32 + (lane >> 1)];
        float ha = (lane & 1) ? bfhi(ua) : bflo(ua);
        float hb = (lane & 1) ? bfhi(ub) : bflo(ub);
        float acc0 = bias, acc1 = bias;
#pragma unroll
        for (int k = 0; k < 64; ++k) {
            float wv = Wt[k * 65 + lane];
            acc0 = fmaf(rl(ha, k), wv, acc0);
            acc1 = fmaf(rl(hb, k), wv, acc1);
        }
        out[(size_t)n0 * HID + lane] = acc0;
        if (v1) out[(size_t)n1 * HID + lane] = acc1;
    }
}

extern "C" void kernel_launch(void* const* d_in, const int* in_sizes, int n_in,
                              void* d_out, int out_size, void* d_ws, size_t ws_size,
                              hipStream_t stream) {
    const float* x      = (const float*)d_in[0];
    const int*   ei     = (const int*)d_in[1];
    const float* lin0_w = (const float*)d_in[2];
    const float* lin0_b = (const float*)d_in[3];
    const float* lin1_w = (const float*)d_in[4];
    const float* lin1_b = (const float*)d_in[5];
    const float* conv_w = (const float*)d_in[6];

    int N = in_sizes[0] / IN_C;
    int E = in_sizes[1] / 2;
    const int* src = ei;
    const int* dst = ei + E;

    // bf16 state buffers: N*64*2B = N*32 uints each
    unsigned* h0 = (unsigned*)d_ws;
    unsigned* hA = h0 + (size_t)N * 32;
    unsigned* hB = hA + (size_t)N * 32;
    int* row_ptr    = (int*)(hB + (size_t)N * 32);
    int* cursor     = row_ptr + (N + 1);
    int* col_idx    = cursor + N;
    int* chunk_sums = col_idx + E;

    int nch = (N + 1023) / 1024;

    // CSR build
    hipMemsetAsync(cursor, 0, (size_t)N * sizeof(int), stream);
    k_hist<<<(E + 255) / 256, 256, 0, stream>>>(dst, cursor, E);
    k_scan_block<<<nch, 1024, 0, stream>>>(cursor, row_ptr, chunk_sums, N);
    k_scan_fix<<<nch, 1024, 0, stream>>>(row_ptr, chunk_sums, N, E);
    hipMemsetAsync(cursor, 0, (size_t)N * sizeof(int), stream);
    k_fill<<<(E + 255) / 256, 256, 0, stream>>>(src, dst, row_ptr, cursor, col_idx, E);

    // input projection -> h0 (bf16)
    k_lin0<<<1024, 256, 0, stream>>>(x, lin0_w, lin0_b, h0, N);

    // 16 fused layers
    const unsigned* cur = h0;
    for (int l = 0; l < 16; ++l) {
        float beta = (float)log(0.5 / (double)(l + 1) + 1.0);
        unsigned* nxt = (l & 1) ? hB : hA;
        k_layer<<<2048, 256, 0, stream>>>((const uint4*)cur, (const uint4*)h0, nxt,
                                          conv_w + (size_t)l * HID * HID,
                                          row_ptr, col_idx, beta, N);
        cur = nxt;
    }

    // output projection
    k_lin1<<<1024, 256, 0, stream>>>(cur, lin1_w, lin1_b, (float*)d_out, N);
}